// Round 9
// baseline (316.013 us; speedup 1.0000x reference)
//
#include <hip/hip_runtime.h>
#include <hip/hip_bf16.h>

#define NB 8
#define CC 256
#define OO 768
#define LL 512
#define VV 25
#define PP 3
#define KM 768
#define NKC 24          // K-chunks of 32
#define LT 4            // l's per block

typedef __attribute__((ext_vector_type(8))) short short8v;
typedef __attribute__((ext_vector_type(4))) float float4v;
typedef __attribute__((ext_vector_type(4))) int int4v;

__device__ inline unsigned pk2(float a, float b){
    __hip_bfloat16 ha = __float2bfloat16(a), hb = __float2bfloat16(b);
    unsigned short ua = *(unsigned short*)&ha, ub = *(unsigned short*)&hb;
    return (unsigned)ua | ((unsigned)ub << 16);
}

// ---------------------------------------------------------------------------
// W -> fragment-ordered bf16 layout in d_ws (validated rounds 6-8):
//   idx = (((kc*4 + wm)*4 + mt)*64 + lane)*8 + j
//   holds W'[c][k], c = wm*64+mt*16+(lane&15), k = kc*32+(lane>>4)*8+j
//   W'[c][k] = W[(p*256+c)*256 + ci], k = cib*192+p*64+ci6, ci = cib*64+ci6.
// ---------------------------------------------------------------------------
__global__ __launch_bounds__(256) void wperm_kernel(const float* __restrict__ W,
                                                    __hip_bfloat16* __restrict__ Wp) {
    int idx = blockIdx.x * 256 + threadIdx.x;
    if (idx >= OO * CC) return;
    int j    = idx & 7;
    int lane = (idx >> 3) & 63;
    int mt   = (idx >> 9) & 3;
    int wm   = (idx >> 11) & 3;
    int kc   = idx >> 13;                    // 0..23
    int c = wm * 64 + mt * 16 + (lane & 15);
    int k = kc * 32 + ((lane >> 4) << 3) + j;
    int cib = k / 192;
    int r = k - cib * 192;
    int p = r >> 6;
    int ci = cib * 64 + (r & 63);
    Wp[idx] = __float2bfloat16(W[(p * 256 + c) * 256 + ci]);
}

// ---------------------------------------------------------------------------
// Fused: window-sum + Z-gen(1-ahead, dbuf) + K=768 MFMA GEMM + BN/relu/res.
// Round-6 structure (best measured) + af register rotation + async xsh-stage
// split (loads spread over kc bodies, ds_write at cib boundary).
// Block = (n, 4 l's). 512 threads / 8 waves.
// ---------------------------------------------------------------------------
__global__ __launch_bounds__(512, 3) void fused_main_kernel(
    const float* __restrict__ x,
    const __hip_bfloat16* __restrict__ Wp,
    const float* __restrict__ A,
    const float* __restrict__ gamma, const float* __restrict__ beta,
    const float* __restrict__ mean, const float* __restrict__ var,
    float* __restrict__ out)
{
    __shared__ __hip_bfloat16 Zb[2][128 * 32];   // Z^T dbuf (16 KB)
    __shared__ __hip_bfloat16 xsh[256 * 32];     // ws-x [ci6*4+l][v pad32] (16 KB)
    __shared__ __hip_bfloat16 a2t[3 * 32 * 32];  // A^T [p*32+w][v pad32] (6 KB)
    __shared__ float scsh[512];                  // 2 KB

    const int tid  = threadIdx.x;
    const int lane = tid & 63, wid = tid >> 6;
    const int lcol = lane & 15, grp = lane >> 4;
    const int bid0 = blockIdx.x;
    const int swz = (bid0 & 7) * 128 + (bid0 >> 3);   // XCD-contiguous chunks
    const int n  = swz >> 7;
    const int l0 = (swz & 127) * LT;
    const int wm = wid >> 1, wn = wid & 1;       // main-GEMM wave grid 4M x 2N
    const int l_z = wid >> 1, mt_z = wid & 1;    // zgen wave roles

    // ---- prologue: zero pads, BN coefs ----
    {
        int4v z = {0, 0, 0, 0};
        ((int4v*)xsh)[tid] = z;
        ((int4v*)xsh)[tid + 512] = z;
        if (tid < 384) ((int4v*)a2t)[tid] = z;
        int c = tid & 255;
        float sc = gamma[c] * rsqrtf(var[c] + 1e-5f);
        if (tid < 256) scsh[tid] = sc;
        else           scsh[tid] = beta[c] - mean[c] * sc;
    }
    __syncthreads();
    // A^T scatter: a2t[p*32 + w][v ^ swz]  (validated r4-r8)
    for (int idx = tid; idx < PP * VV * VV; idx += 512) {
        int p = idx / 625, r = idx - p * 625, v = r / 25, w = r - v * 25;
        int R = p * 32 + w;
        int e = (((v >> 3) ^ ((R >> 1) & 3)) << 3) | (v & 7);
        a2t[R * 32 + e] = __float2bfloat16(A[idx]);
    }

    auto stage_xs = [&](int cib) {               // cold-start staging (cib 0 only)
        for (int cc = tid; cc < 1600; cc += 512) {
            int ci6 = cc / 25, v = cc - ci6 * 25;
            const float* xp = x + ((size_t)(n * CC + cib * 64 + ci6) * LL) * VV + v;
            float rbuf[12];
            #pragma unroll
            for (int j = 0; j < 12; ++j) {
                int lj = l0 - 8 + j;
                rbuf[j] = (lj >= 0) ? xp[(size_t)lj * VV] : 0.f;
            }
            float wsv = 0.f;
            #pragma unroll
            for (int j = 0; j < 9; ++j) wsv += rbuf[j];
            #pragma unroll
            for (int i = 0; i < LT; ++i) {
                int R = ci6 * 4 + i;
                int e = (((v >> 3) ^ ((R >> 2) & 3)) << 3) | (v & 7);
                xsh[R * 32 + e] = __float2bfloat16(wsv);
                if (i < LT - 1) wsv += rbuf[9 + i] - rbuf[i];
            }
        }
    };
    auto zgen = [&](int p, int h, int zbuf) {
        int ci6 = h * 32 + mt_z * 16 + lcol;
        int R = ci6 * 4 + l_z;
        short8v az = *(const short8v*)&xsh[R * 32 + ((grp ^ ((R >> 2) & 3)) << 3)];
        #pragma unroll
        for (int wt = 0; wt < 2; ++wt) {
            int R2 = p * 32 + wt * 16 + lcol;
            short8v bz = *(const short8v*)&a2t[R2 * 32 + ((grp ^ ((R2 >> 1) & 3)) << 3)];
            float4v zc = {0.f, 0.f, 0.f, 0.f};
            zc = __builtin_amdgcn_mfma_f32_16x16x32_bf16(az, bz, zc, 0, 0, 0);
            int R3 = l_z * 32 + wt * 16 + lcol;
            int eb = (mt_z * 2 + (grp >> 1)) ^ ((R3 >> 1) & 3);
            unsigned* dst = (unsigned*)&Zb[zbuf][R3 * 32 + (eb << 3) + ((grp & 1) << 2)];
            dst[0] = pk2(zc[0], zc[1]);
            dst[1] = pk2(zc[2], zc[3]);
        }
    };

    float4v acc[4][4];
    #pragma unroll
    for (int i = 0; i < 4; ++i)
        #pragma unroll
        for (int j = 0; j < 4; ++j) acc[i][j] = (float4v){0.f, 0.f, 0.f, 0.f};

    const __hip_bfloat16* afbase = Wp + ((size_t)(wm * 4) * 64 + lane) * 8;
    unsigned q[8];                               // staged next-cib window sums
    short8v afA[4], afB[4];

    // ---- cold prologue: stage cib 0, prime Z chunk 0 and afA ----
    stage_xs(0);
    asm volatile("s_waitcnt lgkmcnt(0)" ::: "memory");
    __builtin_amdgcn_sched_barrier(0);
    __builtin_amdgcn_s_barrier();

    zgen(0, 0, 0);
    #pragma unroll
    for (int mt = 0; mt < 4; ++mt) afA[mt] = *(const short8v*)(afbase + mt * 512);
    asm volatile("s_waitcnt lgkmcnt(0)" ::: "memory");
    __builtin_amdgcn_sched_barrier(0);
    __builtin_amdgcn_s_barrier();

// One K-chunk step: af prefetch, stage-loads (early), zgen ahead, bf reads,
// 16 MFMAs, stage-sums (late, hide under load latency), lgkm drain + barrier.
#define KSTEP(J, IT, AFC, AFN) do {                                           \
    const int kc_ = base + (J);                                               \
    if (kc_ + 1 < NKC) {                                                      \
        const __hip_bfloat16* ap_ = afbase + (size_t)(kc_ + 1) * 8192;        \
        _Pragma("unroll")                                                     \
        for (int mt_ = 0; mt_ < 4; ++mt_)                                     \
            AFN[mt_] = *(const short8v*)(ap_ + mt_ * 512);                    \
    }                                                                         \
    float rb_[12]; int ci6_ = 0, v_ = 0; bool act_ = false;                   \
    if ((IT) >= 0 && cib < 3) {                                               \
        int cc_ = tid + (IT) * 512; act_ = cc_ < 1600;                        \
        if (act_) {                                                           \
            ci6_ = cc_ / 25; v_ = cc_ - ci6_ * 25;                            \
            const float* xp_ = x + ((size_t)(n * CC + (cib + 1) * 64 + ci6_) * LL) * VV + v_; \
            _Pragma("unroll")                                                 \
            for (int jx_ = 0; jx_ < 12; ++jx_) {                              \
                int lj_ = l0 - 8 + jx_;                                       \
                rb_[jx_] = (lj_ >= 0) ? xp_[(size_t)lj_ * VV] : 0.f;          \
            }                                                                 \
        }                                                                     \
    }                                                                         \
    if ((J) < 5) zgen((((J) + 1) >> 1) & 3, ((J) + 1) & 1, ((J) + 1) & 1);    \
    {                                                                         \
        const __hip_bfloat16* zcur_ = &Zb[(J) & 1][0];                        \
        short8v bf_[4];                                                       \
        _Pragma("unroll")                                                     \
        for (int nt_ = 0; nt_ < 4; ++nt_) {                                   \
            int R3_ = wn * 64 + nt_ * 16 + lcol;                              \
            bf_[nt_] = *(const short8v*)&zcur_[R3_ * 32 + ((grp ^ ((R3_ >> 1) & 3)) << 3)]; \
        }                                                                     \
        __builtin_amdgcn_s_setprio(1);                                        \
        _Pragma("unroll")                                                     \
        for (int mt_ = 0; mt_ < 4; ++mt_)                                     \
            _Pragma("unroll")                                                 \
            for (int nt_ = 0; nt_ < 4; ++nt_)                                 \
                acc[mt_][nt_] = __builtin_amdgcn_mfma_f32_16x16x32_bf16(AFC[mt_], bf_[nt_], acc[mt_][nt_], 0, 0, 0); \
        __builtin_amdgcn_s_setprio(0);                                        \
    }                                                                         \
    if ((IT) >= 0 && act_) {                                                  \
        float w0_ = 0.f;                                                      \
        _Pragma("unroll")                                                     \
        for (int jx_ = 0; jx_ < 9; ++jx_) w0_ += rb_[jx_];                    \
        float w1_ = w0_ + rb_[9]  - rb_[0];                                   \
        float w2_ = w1_ + rb_[10] - rb_[1];                                   \
        float w3_ = w2_ + rb_[11] - rb_[2];                                   \
        q[(IT) * 2]     = pk2(w0_, w1_);                                      \
        q[(IT) * 2 + 1] = pk2(w2_, w3_);                                      \
    }                                                                         \
    asm volatile("s_waitcnt lgkmcnt(0)" ::: "memory");                        \
    __builtin_amdgcn_sched_barrier(0);                                        \
    __builtin_amdgcn_s_barrier();                                             \
} while (0)

    #pragma unroll 1
    for (int cib = 0; cib < 4; ++cib) {
        const int base = cib * 6;
        KSTEP(0, -1, afA, afB);
        KSTEP(1,  0, afB, afA);
        KSTEP(2,  1, afA, afB);
        KSTEP(3,  2, afB, afA);
        KSTEP(4,  3, afA, afB);
        KSTEP(5, -1, afB, afA);

        if (cib < 3) {
            // write staged window sums for cib+1 (xsh fully consumed above)
            #pragma unroll
            for (int it = 0; it < 4; ++it) {
                int cc = tid + it * 512;
                if (cc < 1600) {
                    int ci6 = cc / 25, v = cc - ci6 * 25;
                    unsigned lo = q[it * 2], hi = q[it * 2 + 1];
                    unsigned short hh0 = (unsigned short)(lo & 0xffff);
                    unsigned short hh1 = (unsigned short)(lo >> 16);
                    unsigned short hh2 = (unsigned short)(hi & 0xffff);
                    unsigned short hh3 = (unsigned short)(hi >> 16);
                    int e0 = (((v >> 3) ^ (((ci6 * 4 + 0) >> 2) & 3)) << 3) | (v & 7);
                    *(unsigned short*)&xsh[(ci6 * 4 + 0) * 32 + e0] = hh0;
                    int e1 = (((v >> 3) ^ (((ci6 * 4 + 1) >> 2) & 3)) << 3) | (v & 7);
                    *(unsigned short*)&xsh[(ci6 * 4 + 1) * 32 + e1] = hh1;
                    int e2 = (((v >> 3) ^ (((ci6 * 4 + 2) >> 2) & 3)) << 3) | (v & 7);
                    *(unsigned short*)&xsh[(ci6 * 4 + 2) * 32 + e2] = hh2;
                    int e3 = (((v >> 3) ^ (((ci6 * 4 + 3) >> 2) & 3)) << 3) | (v & 7);
                    *(unsigned short*)&xsh[(ci6 * 4 + 3) * 32 + e3] = hh3;
                }
            }
            asm volatile("s_waitcnt lgkmcnt(0)" ::: "memory");
            __builtin_amdgcn_sched_barrier(0);
            __builtin_amdgcn_s_barrier();

            zgen(0, 0, 0);                       // prime Z for next cib (kc%6==0)
            asm volatile("s_waitcnt lgkmcnt(0)" ::: "memory");
            __builtin_amdgcn_sched_barrier(0);
            __builtin_amdgcn_s_barrier();
        }
    }
#undef KSTEP

    // ---- epilogue: BN + relu + residual + relu + store (validated r4-r8) ----
    #pragma unroll
    for (int mt = 0; mt < 4; ++mt) {
        #pragma unroll
        for (int nt = 0; nt < 4; ++nt) {
            int lw = (wn * 64 + nt * 16);
            int w = lw & 31;
            int l = l0 + (lw >> 5);
            int wl = w + lcol;
            if (wl < VV) {
                #pragma unroll
                for (int r = 0; r < 4; ++r) {
                    int c = wm * 64 + mt * 16 + grp * 4 + r;
                    float val = fmaf(acc[mt][nt][r], scsh[c], scsh[256 + c]);
                    val = fmaxf(val, 0.f);
                    size_t ad = ((size_t)(n * CC + c) * LL + l) * VV + wl;
                    val = fmaxf(val + x[ad], 0.f);
                    out[ad] = val;
                }
            }
        }
    }
}

// ===========================================================================
// Fallback path (ws too small): round-1/2 proven kernels (in-place on d_out)
// ===========================================================================
__global__ __launch_bounds__(256) void wsum_kernel(const float* __restrict__ x,
                                                   float* __restrict__ xs) {
    const int CHUNKS = 8;
    int t = blockIdx.x * 256 + threadIdx.x;
    if (t >= NB * CC * VV * CHUNKS) return;
    int v = t % VV;
    int r = t / VV;
    int chunk = r % CHUNKS;
    int nc = r / CHUNKS;
    int l0 = chunk * (LL / CHUNKS);
    const float* xp = x  + (size_t)nc * (LL * VV) + v;
    float*       op = xs + (size_t)nc * (LL * VV) + v;
    float ring[8];
    float run = 0.f;
    #pragma unroll
    for (int k = 0; k < 8; ++k) {
        int j = l0 - 8 + k;
        float val = (j >= 0) ? xp[j * VV] : 0.f;
        ring[k] = val; run += val;
    }
    for (int base = l0; base < l0 + LL / CHUNKS; base += 8) {
        #pragma unroll
        for (int k = 0; k < 8; ++k) {
            int l = base + k;
            float val = xp[l * VV];
            float o = run + val;
            op[l * VV] = o;
            run = o - ring[k];
            ring[k] = val;
        }
    }
}

__global__ __launch_bounds__(256) void fused_fallback_kernel(
    const float* xs, const float* __restrict__ x, const float* __restrict__ W,
    const float* __restrict__ A,
    const float* __restrict__ gamma, const float* __restrict__ beta,
    const float* __restrict__ mean, const float* __restrict__ var,
    float* out)
{
    __shared__ float xshf[CC][28];
    const int bid = blockIdx.x;
    const int n = bid >> 9;
    const int l = bid & 511;
    const int tid = threadIdx.x;
    const size_t nbase = (size_t)n * CC * LL * VV;
    for (int k = tid; k < CC * VV; k += 256) {
        int ci = k / VV, v = k - ci * VV;
        xshf[ci][v] = xs[nbase + (size_t)ci * (LL * VV) + (size_t)l * VV + v];
    }
    __syncthreads();
    const int c = tid;
    float Y[PP * VV];
    #pragma unroll
    for (int i = 0; i < PP * VV; ++i) Y[i] = 0.f;
    const float* Wpr = W + c * 256;
    #pragma unroll 1
    for (int ci = 0; ci < CC; ++ci) {
        float xv[VV];
        #pragma unroll
        for (int v = 0; v < VV; ++v) xv[v] = xshf[ci][v];
        float w0 = Wpr[ci], w1 = Wpr[65536 + ci], w2 = Wpr[131072 + ci];
        #pragma unroll
        for (int v = 0; v < VV; ++v) Y[v]          = fmaf(w0, xv[v], Y[v]);
        #pragma unroll
        for (int v = 0; v < VV; ++v) Y[VV + v]     = fmaf(w1, xv[v], Y[VV + v]);
        #pragma unroll
        for (int v = 0; v < VV; ++v) Y[2 * VV + v] = fmaf(w2, xv[v], Y[2 * VV + v]);
    }
    float o[VV];
    #pragma unroll
    for (int w = 0; w < VV; ++w) o[w] = 0.f;
    #pragma unroll
    for (int p = 0; p < PP; ++p)
        #pragma unroll
        for (int v = 0; v < VV; ++v) {
            float y = Y[p * VV + v];
            const float* Ap = A + (p * VV + v) * VV;
            #pragma unroll
            for (int w = 0; w < VV; ++w) o[w] = fmaf(y, Ap[w], o[w]);
        }
    float sc = gamma[c] * rsqrtf(var[c] + 1e-5f);
    float sh = beta[c] - mean[c] * sc;
    const float* resp = x   + nbase + (size_t)c * (LL * VV) + (size_t)l * VV;
    float*       outp = out + nbase + (size_t)c * (LL * VV) + (size_t)l * VV;
    #pragma unroll
    for (int w = 0; w < VV; ++w) {
        float t2 = fmaf(o[w], sc, sh);
        t2 = fmaxf(t2, 0.f);
        t2 = fmaxf(t2 + resp[w], 0.f);
        outp[w] = t2;
    }
}

extern "C" void kernel_launch(void* const* d_in, const int* in_sizes, int n_in,
                              void* d_out, int out_size, void* d_ws, size_t ws_size,
                              hipStream_t stream) {
    const float* x  = (const float*)d_in[0];
    const float* W  = (const float*)d_in[1];
    const float* A  = (const float*)d_in[2];
    const float* gm = (const float*)d_in[3];
    const float* bt = (const float*)d_in[4];
    const float* mn = (const float*)d_in[5];
    const float* vr = (const float*)d_in[6];
    float* out = (float*)d_out;

    if (ws_size >= (size_t)(OO * CC * sizeof(__hip_bfloat16))) {
        __hip_bfloat16* Wp = (__hip_bfloat16*)d_ws;
        wperm_kernel<<<dim3((OO * CC + 255) / 256), dim3(256), 0, stream>>>(W, Wp);
        fused_main_kernel<<<dim3(NB * (LL / LT)), dim3(512), 0, stream>>>(
            x, Wp, A, gm, bt, mn, vr, out);
    } else {
        const int threadsA = NB * CC * VV * 8;
        wsum_kernel<<<dim3((threadsA + 255) / 256), dim3(256), 0, stream>>>(x, out);
        fused_fallback_kernel<<<dim3(NB * LL), dim3(256), 0, stream>>>(
            out, x, W, A, gm, bt, mn, vr, out);
    }
}

// Round 10
// 107.045 us; speedup vs baseline: 2.9521x; 2.9521x over previous
//
#include <hip/hip_runtime.h>
#include <hip/hip_bf16.h>

#define NB 8
#define CC 256
#define OO 768
#define LL 512
#define VV 25
#define PP 3
#define KM 768
#define NKC 24          // K-chunks of 32
#define LT 4            // l's per block

typedef __attribute__((ext_vector_type(8))) short short8v;
typedef __attribute__((ext_vector_type(4))) float float4v;
typedef __attribute__((ext_vector_type(4))) int int4v;

__device__ inline unsigned pk2(float a, float b){
    __hip_bfloat16 ha = __float2bfloat16(a), hb = __float2bfloat16(b);
    unsigned short ua = *(unsigned short*)&ha, ub = *(unsigned short*)&hb;
    return (unsigned)ua | ((unsigned)ub << 16);
}

// ---------------------------------------------------------------------------
// W -> fragment-ordered bf16 layout in d_ws (validated rounds 6-9):
//   idx = (((kc*4 + wm)*4 + mt)*64 + lane)*8 + j
//   holds W'[c][k], c = wm*64+mt*16+(lane&15), k = kc*32+(lane>>4)*8+j
//   W'[c][k] = W[(p*256+c)*256 + ci], k = cib*192+p*64+ci6, ci = cib*64+ci6.
// ---------------------------------------------------------------------------
__global__ __launch_bounds__(256) void wperm_kernel(const float* __restrict__ W,
                                                    __hip_bfloat16* __restrict__ Wp) {
    int idx = blockIdx.x * 256 + threadIdx.x;
    if (idx >= OO * CC) return;
    int j    = idx & 7;
    int lane = (idx >> 3) & 63;
    int mt   = (idx >> 9) & 3;
    int wm   = (idx >> 11) & 3;
    int kc   = idx >> 13;                    // 0..23
    int c = wm * 64 + mt * 16 + (lane & 15);
    int k = kc * 32 + ((lane >> 4) << 3) + j;
    int cib = k / 192;
    int r = k - cib * 192;
    int p = r >> 6;
    int ci = cib * 64 + (r & 63);
    Wp[idx] = __float2bfloat16(W[(p * 256 + c) * 256 + ci]);
}

// ---------------------------------------------------------------------------
// Fused: window-sum + BULK Z-gen per cib + barrier-free 6-chunk MFMA run +
// BN/relu/residual. Block = (n, 4 l's), 512 threads / 8 waves.
// Per cib: [bar] stage_xs [bar] zgen_all (12 MFMA/wave -> 48 KB Z) [bar]
// then 6 K-chunks of pure {af L2-load, bf ds_read, 16 MFMA} with NO fences —
// compiler is free to software-pipeline the whole run.
// ---------------------------------------------------------------------------
__global__ __launch_bounds__(512, 4) void fused_main_kernel(
    const float* __restrict__ x,
    const __hip_bfloat16* __restrict__ Wp,
    const float* __restrict__ A,
    const float* __restrict__ gamma, const float* __restrict__ beta,
    const float* __restrict__ mean, const float* __restrict__ var,
    float* __restrict__ out)
{
    __shared__ __hip_bfloat16 Zb[6][128 * 32];   // whole-cib Z (48 KB)
    __shared__ __hip_bfloat16 xsh[256 * 32];     // ws-x [ci6*4+l][v pad32] (16 KB)
    __shared__ __hip_bfloat16 a2t[3 * 32 * 32];  // A^T [p*32+w][v pad32] (6 KB)
    __shared__ float scsh[512];                  // 2 KB

    const int tid  = threadIdx.x;
    const int lane = tid & 63, wid = tid >> 6;
    const int lcol = lane & 15, grp = lane >> 4;
    const int bid0 = blockIdx.x;
    const int swz = (bid0 & 7) * 128 + (bid0 >> 3);   // XCD-contiguous chunks
    const int n  = swz >> 7;
    const int l0 = (swz & 127) * LT;
    const int wm = wid >> 1, wn = wid & 1;       // main-GEMM wave grid 4M x 2N
    const int l_z = wid >> 1, mt_z = wid & 1;    // zgen wave roles

    // ---- prologue: zero pads, BN coefs ----
    {
        int4v z = {0, 0, 0, 0};
        ((int4v*)xsh)[tid] = z;
        ((int4v*)xsh)[tid + 512] = z;
        if (tid < 384) ((int4v*)a2t)[tid] = z;
        int c = tid & 255;
        float sc = gamma[c] * rsqrtf(var[c] + 1e-5f);
        if (tid < 256) scsh[tid] = sc;
        else           scsh[tid] = beta[c] - mean[c] * sc;
    }
    __syncthreads();
    // A^T scatter: a2t[p*32 + w][v ^ swz]  (validated r4-r9)
    for (int idx = tid; idx < PP * VV * VV; idx += 512) {
        int p = idx / 625, r = idx - p * 625, v = r / 25, w = r - v * 25;
        int R = p * 32 + w;
        int e = (((v >> 3) ^ ((R >> 1) & 3)) << 3) | (v & 7);
        a2t[R * 32 + e] = __float2bfloat16(A[idx]);
    }

    auto stage_xs = [&](int cib) {
        for (int cc = tid; cc < 1600; cc += 512) {
            int ci6 = cc / 25, v = cc - ci6 * 25;
            const float* xp = x + ((size_t)(n * CC + cib * 64 + ci6) * LL) * VV + v;
            float rbuf[12];
            #pragma unroll
            for (int j = 0; j < 12; ++j) {
                int lj = l0 - 8 + j;
                rbuf[j] = (lj >= 0) ? xp[(size_t)lj * VV] : 0.f;
            }
            float wsv = 0.f;
            #pragma unroll
            for (int j = 0; j < 9; ++j) wsv += rbuf[j];
            #pragma unroll
            for (int i = 0; i < LT; ++i) {
                int R = ci6 * 4 + i;
                int e = (((v >> 3) ^ ((R >> 2) & 3)) << 3) | (v & 7);
                xsh[R * 32 + e] = __float2bfloat16(wsv);
                if (i < LT - 1) wsv += rbuf[9 + i] - rbuf[i];
            }
        }
    };

    // bulk Z-gen: all 6 chunks of this cib (j = p*2 + h, matching kc%6)
    auto zgen_all = [&]() {
        short8v az[2];
        #pragma unroll
        for (int h = 0; h < 2; ++h) {
            int ci6 = h * 32 + mt_z * 16 + lcol;
            int R = ci6 * 4 + l_z;
            az[h] = *(const short8v*)&xsh[R * 32 + ((grp ^ ((R >> 2) & 3)) << 3)];
        }
        #pragma unroll
        for (int p = 0; p < PP; ++p) {
            #pragma unroll
            for (int wt = 0; wt < 2; ++wt) {
                int R2 = p * 32 + wt * 16 + lcol;
                short8v bz = *(const short8v*)&a2t[R2 * 32 + ((grp ^ ((R2 >> 1) & 3)) << 3)];
                #pragma unroll
                for (int h = 0; h < 2; ++h) {
                    float4v zc = {0.f, 0.f, 0.f, 0.f};
                    zc = __builtin_amdgcn_mfma_f32_16x16x32_bf16(az[h], bz, zc, 0, 0, 0);
                    int R3 = l_z * 32 + wt * 16 + lcol;
                    int eb = (mt_z * 2 + (grp >> 1)) ^ ((R3 >> 1) & 3);
                    unsigned* dst = (unsigned*)&Zb[p * 2 + h][R3 * 32 + (eb << 3) + ((grp & 1) << 2)];
                    dst[0] = pk2(zc[0], zc[1]);
                    dst[1] = pk2(zc[2], zc[3]);
                }
            }
        }
    };

    float4v acc[4][4];
    #pragma unroll
    for (int i = 0; i < 4; ++i)
        #pragma unroll
        for (int j = 0; j < 4; ++j) acc[i][j] = (float4v){0.f, 0.f, 0.f, 0.f};

    const __hip_bfloat16* afbase = Wp + ((size_t)(wm * 4) * 64 + lane) * 8;

    #pragma unroll 1
    for (int cib = 0; cib < 4; ++cib) {
        __syncthreads();                 // prev-cib Zb consumed; a2t/xsh-pads visible
        stage_xs(cib);
        __syncthreads();
        zgen_all();
        __syncthreads();

        // barrier-free consumption: 6 chunks, compiler-scheduled
        #pragma unroll
        for (int j = 0; j < 6; ++j) {
            const int kc = cib * 6 + j;
            short8v af[4];
            {
                const __hip_bfloat16* ap = afbase + (size_t)kc * 8192;
                #pragma unroll
                for (int mt = 0; mt < 4; ++mt)
                    af[mt] = *(const short8v*)(ap + mt * 512);
            }
            short8v bf[4];
            #pragma unroll
            for (int nt = 0; nt < 4; ++nt) {
                int R3 = wn * 64 + nt * 16 + lcol;
                bf[nt] = *(const short8v*)&Zb[j][R3 * 32 + ((grp ^ ((R3 >> 1) & 3)) << 3)];
            }
            #pragma unroll
            for (int mt = 0; mt < 4; ++mt)
                #pragma unroll
                for (int nt = 0; nt < 4; ++nt)
                    acc[mt][nt] = __builtin_amdgcn_mfma_f32_16x16x32_bf16(af[mt], bf[nt], acc[mt][nt], 0, 0, 0);
        }
    }

    // ---- epilogue: BN + relu + residual + relu + store (validated r4-r9) ----
    #pragma unroll
    for (int mt = 0; mt < 4; ++mt) {
        #pragma unroll
        for (int nt = 0; nt < 4; ++nt) {
            int lw = (wn * 64 + nt * 16);
            int w = lw & 31;
            int l = l0 + (lw >> 5);
            int wl = w + lcol;
            if (wl < VV) {
                #pragma unroll
                for (int r = 0; r < 4; ++r) {
                    int c = wm * 64 + mt * 16 + grp * 4 + r;
                    float val = fmaf(acc[mt][nt][r], scsh[c], scsh[256 + c]);
                    val = fmaxf(val, 0.f);
                    size_t ad = ((size_t)(n * CC + c) * LL + l) * VV + wl;
                    val = fmaxf(val + x[ad], 0.f);
                    out[ad] = val;
                }
            }
        }
    }
}

// ===========================================================================
// Fallback path (ws too small): round-1/2 proven kernels (in-place on d_out)
// ===========================================================================
__global__ __launch_bounds__(256) void wsum_kernel(const float* __restrict__ x,
                                                   float* __restrict__ xs) {
    const int CHUNKS = 8;
    int t = blockIdx.x * 256 + threadIdx.x;
    if (t >= NB * CC * VV * CHUNKS) return;
    int v = t % VV;
    int r = t / VV;
    int chunk = r % CHUNKS;
    int nc = r / CHUNKS;
    int l0 = chunk * (LL / CHUNKS);
    const float* xp = x  + (size_t)nc * (LL * VV) + v;
    float*       op = xs + (size_t)nc * (LL * VV) + v;
    float ring[8];
    float run = 0.f;
    #pragma unroll
    for (int k = 0; k < 8; ++k) {
        int j = l0 - 8 + k;
        float val = (j >= 0) ? xp[j * VV] : 0.f;
        ring[k] = val; run += val;
    }
    for (int base = l0; base < l0 + LL / CHUNKS; base += 8) {
        #pragma unroll
        for (int k = 0; k < 8; ++k) {
            int l = base + k;
            float val = xp[l * VV];
            float o = run + val;
            op[l * VV] = o;
            run = o - ring[k];
            ring[k] = val;
        }
    }
}

__global__ __launch_bounds__(256) void fused_fallback_kernel(
    const float* xs, const float* __restrict__ x, const float* __restrict__ W,
    const float* __restrict__ A,
    const float* __restrict__ gamma, const float* __restrict__ beta,
    const float* __restrict__ mean, const float* __restrict__ var,
    float* out)
{
    __shared__ float xshf[CC][28];
    const int bid = blockIdx.x;
    const int n = bid >> 9;
    const int l = bid & 511;
    const int tid = threadIdx.x;
    const size_t nbase = (size_t)n * CC * LL * VV;
    for (int k = tid; k < CC * VV; k += 256) {
        int ci = k / VV, v = k - ci * VV;
        xshf[ci][v] = xs[nbase + (size_t)ci * (LL * VV) + (size_t)l * VV + v];
    }
    __syncthreads();
    const int c = tid;
    float Y[PP * VV];
    #pragma unroll
    for (int i = 0; i < PP * VV; ++i) Y[i] = 0.f;
    const float* Wpr = W + c * 256;
    #pragma unroll 1
    for (int ci = 0; ci < CC; ++ci) {
        float xv[VV];
        #pragma unroll
        for (int v = 0; v < VV; ++v) xv[v] = xshf[ci][v];
        float w0 = Wpr[ci], w1 = Wpr[65536 + ci], w2 = Wpr[131072 + ci];
        #pragma unroll
        for (int v = 0; v < VV; ++v) Y[v]          = fmaf(w0, xv[v], Y[v]);
        #pragma unroll
        for (int v = 0; v < VV; ++v) Y[VV + v]     = fmaf(w1, xv[v], Y[VV + v]);
        #pragma unroll
        for (int v = 0; v < VV; ++v) Y[2 * VV + v] = fmaf(w2, xv[v], Y[2 * VV + v]);
    }
    float o[VV];
    #pragma unroll
    for (int w = 0; w < VV; ++w) o[w] = 0.f;
    #pragma unroll
    for (int p = 0; p < PP; ++p)
        #pragma unroll
        for (int v = 0; v < VV; ++v) {
            float y = Y[p * VV + v];
            const float* Ap = A + (p * VV + v) * VV;
            #pragma unroll
            for (int w = 0; w < VV; ++w) o[w] = fmaf(y, Ap[w], o[w]);
        }
    float sc = gamma[c] * rsqrtf(var[c] + 1e-5f);
    float sh = beta[c] - mean[c] * sc;
    const float* resp = x   + nbase + (size_t)c * (LL * VV) + (size_t)l * VV;
    float*       outp = out + nbase + (size_t)c * (LL * VV) + (size_t)l * VV;
    #pragma unroll
    for (int w = 0; w < VV; ++w) {
        float t2 = fmaf(o[w], sc, sh);
        t2 = fmaxf(t2, 0.f);
        t2 = fmaxf(t2 + resp[w], 0.f);
        outp[w] = t2;
    }
}

extern "C" void kernel_launch(void* const* d_in, const int* in_sizes, int n_in,
                              void* d_out, int out_size, void* d_ws, size_t ws_size,
                              hipStream_t stream) {
    const float* x  = (const float*)d_in[0];
    const float* W  = (const float*)d_in[1];
    const float* A  = (const float*)d_in[2];
    const float* gm = (const float*)d_in[3];
    const float* bt = (const float*)d_in[4];
    const float* mn = (const float*)d_in[5];
    const float* vr = (const float*)d_in[6];
    float* out = (float*)d_out;

    if (ws_size >= (size_t)(OO * CC * sizeof(__hip_bfloat16))) {
        __hip_bfloat16* Wp = (__hip_bfloat16*)d_ws;
        wperm_kernel<<<dim3((OO * CC + 255) / 256), dim3(256), 0, stream>>>(W, Wp);
        fused_main_kernel<<<dim3(NB * (LL / LT)), dim3(512), 0, stream>>>(
            x, Wp, A, gm, bt, mn, vr, out);
    } else {
        const int threadsA = NB * CC * VV * 8;
        wsum_kernel<<<dim3((threadsA + 255) / 256), dim3(256), 0, stream>>>(x, out);
        fused_fallback_kernel<<<dim3(NB * LL), dim3(256), 0, stream>>>(
            out, x, W, A, gm, bt, mn, vr, out);
    }
}